// Round 2
// baseline (200.569 us; speedup 1.0000x reference)
//
#include <hip/hip_runtime.h>

#define B 8
#define F 2048
#define L 1024
#define BN_EPS 1e-5f
#define THRESH 0.81f
#define ROWS 16   // output rows per block in out_kernel

// native clang vector — required operand type for __builtin_nontemporal_store
typedef float vf4 __attribute__((ext_vector_type(4)));

// ---------------------------------------------------------------------------
// Kernel 1: h[b,f] = mean_L( prelu(x[b,f,:], w1) )
// One wave (64 lanes) per row; 4 rows per 256-thread block; float4 loads.
// Memory-bound: 64 MiB read, ~10 us floor.
// ---------------------------------------------------------------------------
__global__ __launch_bounds__(256) void pool_kernel(const float* __restrict__ x,
                                                   const float* __restrict__ p1,
                                                   float* __restrict__ h) {
    const int wave = threadIdx.x >> 6;
    const int lane = threadIdx.x & 63;
    const int row  = blockIdx.x * 4 + wave;           // [0, B*F)
    const float w = p1[0];
    const float4* xr = (const float4*)(x + (size_t)row * L);
    float sum = 0.f;
#pragma unroll
    for (int k = 0; k < 4; ++k) {
        float4 v = xr[lane + 64 * k];                 // coalesced 16B/lane
        sum += (v.x >= 0.f) ? v.x : w * v.x;
        sum += (v.y >= 0.f) ? v.y : w * v.y;
        sum += (v.z >= 0.f) ? v.z : w * v.z;
        sum += (v.w >= 0.f) ? v.w : w * v.w;
    }
#pragma unroll
    for (int off = 32; off > 0; off >>= 1)
        sum += __shfl_down(sum, off, 64);
    if (lane == 0) h[row] = sum * (1.0f / L);
}

// ---------------------------------------------------------------------------
// Kernel 2: per-channel BatchNorm over the B=8 pooled samples (in place).
// One thread per channel f. Each thread owns all (b,f) elements it writes.
// ---------------------------------------------------------------------------
__global__ __launch_bounds__(256) void bn_kernel(float* __restrict__ h,
                                                 const float* __restrict__ bnw,
                                                 const float* __restrict__ bnb) {
    const int f = blockIdx.x * 256 + threadIdx.x;     // < F
    float v[B];
    float mu = 0.f;
#pragma unroll
    for (int b = 0; b < B; ++b) { v[b] = h[b * F + f]; mu += v[b]; }
    mu *= (1.0f / B);
    float var = 0.f;
#pragma unroll
    for (int b = 0; b < B; ++b) { float d = v[b] - mu; var += d * d; }
    var *= (1.0f / B);
    const float scale = (1.0f / sqrtf(var + BN_EPS)) * bnw[f];
    const float bias  = bnb[f];
#pragma unroll
    for (int b = 0; b < B; ++b) h[b * F + f] = (v[b] - mu) * scale + bias;
}

// ---------------------------------------------------------------------------
// Kernel 3: deg[b,n] = 1 + #{m : hn[b,n]*hn[b,m] > THRESH};  dinv = deg^-1/2.
// Block = 256 threads handles 64 n's of one batch; 4 threads per n split the
// m-range. hn[b,:] (8 KB) lives in LDS; within a wave all lanes read the SAME
// LDS word (broadcast, conflict-free).
// ---------------------------------------------------------------------------
__global__ __launch_bounds__(256) void deg_kernel(const float* __restrict__ hn,
                                                  float* __restrict__ dinv) {
    __shared__ float sh[F];
    __shared__ int partial[4][64];
    const int b    = blockIdx.x / (F / 64);
    const int nblk = blockIdx.x % (F / 64);
    for (int i = threadIdx.x; i < F; i += 256) sh[i] = hn[b * F + i];
    __syncthreads();
    const int nl = threadIdx.x & 63;
    const int q  = threadIdx.x >> 6;                  // == wave id
    const int n  = nblk * 64 + nl;
    const float hv = sh[n];
    int cnt = 0;
    const int m0 = q * (F / 4);
    for (int m = 0; m < F / 4; m += 4) {
        float4 hm = *(const float4*)&sh[m0 + m];      // broadcast ds_read_b128
        cnt += (hv * hm.x > THRESH);
        cnt += (hv * hm.y > THRESH);
        cnt += (hv * hm.z > THRESH);
        cnt += (hv * hm.w > THRESH);
    }
    partial[q][nl] = cnt;
    __syncthreads();
    if (q == 0) {
        int deg = 1 + partial[0][nl] + partial[1][nl] + partial[2][nl] + partial[3][nl];
        dinv[b * F + n] = 1.0f / sqrtf((float)deg);
    }
}

// ---------------------------------------------------------------------------
// Kernel 4 (RESTRUCTURED): out[b,n,m] = prelu2( dn * A[n,m] * dm ).
// One block owns ROWS=16 consecutive n-rows of one batch. hn[b,:] and
// dinv[b,:] (16 KB) are staged into LDS ONCE per block and reused for all 16
// rows — global read traffic drops 16384*16KB=256MiB -> 1024*16KB=16MiB.
// Output (128 MiB, written once, never re-read) uses nontemporal vf4 stores
// (global_store_dwordx4 nt) so the write stream doesn't thrash L2.
// Grid = B*(F/ROWS) = 1024 blocks = 4 blocks/CU (16 waves/CU, LDS 16KB/blk).
// ---------------------------------------------------------------------------
__global__ __launch_bounds__(256) void out_kernel(const float* __restrict__ hn,
                                                  const float* __restrict__ dinv,
                                                  const float* __restrict__ p2,
                                                  float* __restrict__ out) {
    __shared__ float sh_h[F];
    __shared__ float sh_d[F];
    const int b  = blockIdx.x / (F / ROWS);
    const int r0 = (blockIdx.x % (F / ROWS)) * ROWS;
    {
        const float4* hsrc = (const float4*)(hn + b * F);
        const float4* dsrc = (const float4*)(dinv + b * F);
        float4* hdst = (float4*)sh_h;
        float4* ddst = (float4*)sh_d;
        for (int i = threadIdx.x; i < F / 4; i += 256) {
            hdst[i] = hsrc[i];                        // coalesced, L2-served
            ddst[i] = dsrc[i];
        }
    }
    __syncthreads();
    const float w2 = p2[0];
    const float4* sh4 = (const float4*)sh_h;
    const float4* sd4 = (const float4*)sh_d;
    for (int r = 0; r < ROWS; ++r) {
        const int n = r0 + r;
        const float hv = sh_h[n];                     // LDS broadcast
        const float dn = sh_d[n];
        vf4* o4 = (vf4*)(out + (size_t)(b * F + n) * F);
        for (int t = threadIdx.x; t < F / 4; t += 256) {   // 2 iters/thread
            float4 hm = sh4[t];                       // consecutive b128, conflict-free
            float4 dm = sd4[t];
            const int m = t * 4;
            vf4 rr;
            {
                float a = (hv * hm.x > THRESH) ? 1.f : 0.f; if (n == m + 0) a += 1.f;
                float v = (dn * a) * dm.x; rr.x = (v >= 0.f) ? v : w2 * v;
            }
            {
                float a = (hv * hm.y > THRESH) ? 1.f : 0.f; if (n == m + 1) a += 1.f;
                float v = (dn * a) * dm.y; rr.y = (v >= 0.f) ? v : w2 * v;
            }
            {
                float a = (hv * hm.z > THRESH) ? 1.f : 0.f; if (n == m + 2) a += 1.f;
                float v = (dn * a) * dm.z; rr.z = (v >= 0.f) ? v : w2 * v;
            }
            {
                float a = (hv * hm.w > THRESH) ? 1.f : 0.f; if (n == m + 3) a += 1.f;
                float v = (dn * a) * dm.w; rr.w = (v >= 0.f) ? v : w2 * v;
            }
            __builtin_nontemporal_store(rr, &o4[t]);  // global_store_dwordx4 nt
        }
    }
}

extern "C" void kernel_launch(void* const* d_in, const int* in_sizes, int n_in,
                              void* d_out, int out_size, void* d_ws, size_t ws_size,
                              hipStream_t stream) {
    const float* x   = (const float*)d_in[0];
    const float* p1  = (const float*)d_in[1];
    const float* p2  = (const float*)d_in[2];
    const float* bnw = (const float*)d_in[3];
    const float* bnb = (const float*)d_in[4];
    float* out = (float*)d_out;

    float* h    = (float*)d_ws;            // B*F floats (pooled, then BN'd in place)
    float* dinv = h + B * F;               // B*F floats

    pool_kernel<<<(B * F) / 4, 256, 0, stream>>>(x, p1, h);
    bn_kernel<<<F / 256, 256, 0, stream>>>(h, bnw, bnb);
    deg_kernel<<<B * (F / 64), 256, 0, stream>>>(h, dinv);
    out_kernel<<<B * (F / ROWS), 256, 0, stream>>>(h, dinv, p2, out);
}

// Round 3
// 194.958 us; speedup vs baseline: 1.0288x; 1.0288x over previous
//
#include <hip/hip_runtime.h>

#define B 8
#define F 2048
#define L 1024
#define BN_EPS 1e-5f
#define THRESH 0.81f

// ---------------------------------------------------------------------------
// Kernel 1: h[b,f] = mean_L( prelu(x[b,f,:], w1) )
// One wave (64 lanes) per row; 4 rows per 256-thread block; float4 loads.
// Memory-bound: 64 MiB read, ~11 us floor at 6 TB/s.
// ---------------------------------------------------------------------------
__global__ __launch_bounds__(256) void pool_kernel(const float* __restrict__ x,
                                                   const float* __restrict__ p1,
                                                   float* __restrict__ h) {
    const int wave = threadIdx.x >> 6;
    const int lane = threadIdx.x & 63;
    const int row  = blockIdx.x * 4 + wave;           // [0, B*F)
    const float w = p1[0];
    const float4* xr = (const float4*)(x + (size_t)row * L);
    float sum = 0.f;
#pragma unroll
    for (int k = 0; k < 4; ++k) {
        float4 v = xr[lane + 64 * k];                 // coalesced 16B/lane
        sum += (v.x >= 0.f) ? v.x : w * v.x;
        sum += (v.y >= 0.f) ? v.y : w * v.y;
        sum += (v.z >= 0.f) ? v.z : w * v.z;
        sum += (v.w >= 0.f) ? v.w : w * v.w;
    }
#pragma unroll
    for (int off = 32; off > 0; off >>= 1)
        sum += __shfl_down(sum, off, 64);
    if (lane == 0) h[row] = sum * (1.0f / L);
}

// ---------------------------------------------------------------------------
// Kernel 2 (FUSED bn+deg): per-channel BatchNorm over the B=8 pooled samples,
// then deg[b,n] = 1 + #{m : hn[b,n]*hn[b,m] > THRESH}; dinv = deg^-1/2.
//
// Each block (b, nblk) redundantly computes BN stats for all F channels from
// the 64 KB pooled array (L2-resident; 256 blocks x 64 KB = 16 MB L2 reads,
// ~0.5 us) and normalizes its batch's row into LDS. Blocks with nblk==0 also
// write the normalized row to global hn for out_kernel (8 KB/batch).
// Saves one kernel launch + inter-kernel gap vs separate bn_kernel.
// ---------------------------------------------------------------------------
__global__ __launch_bounds__(256) void bndeg_kernel(const float* __restrict__ h,
                                                    const float* __restrict__ bnw,
                                                    const float* __restrict__ bnb,
                                                    float* __restrict__ hn,
                                                    float* __restrict__ dinv) {
    __shared__ float sh[F];                           // normalized row of batch b
    __shared__ int partial[4][64];
    const int b    = blockIdx.x / (F / 64);
    const int nblk = blockIdx.x % (F / 64);

    // --- BN: each thread owns F/256 = 8 channels
#pragma unroll
    for (int k = 0; k < F / 256; ++k) {
        const int f = threadIdx.x + k * 256;          // coalesced across threads
        float vb[B];
        float mu = 0.f;
#pragma unroll
        for (int bb = 0; bb < B; ++bb) { vb[bb] = h[bb * F + f]; mu += vb[bb]; }
        mu *= (1.0f / B);
        float var = 0.f;
#pragma unroll
        for (int bb = 0; bb < B; ++bb) { float d = vb[bb] - mu; var += d * d; }
        var *= (1.0f / B);
        const float scale = (1.0f / sqrtf(var + BN_EPS)) * bnw[f];
        sh[f] = (vb[b] - mu) * scale + bnb[f];
    }
    __syncthreads();

    // --- publish normalized row once per batch
    if (nblk == 0)
        for (int i = threadIdx.x; i < F; i += 256) hn[b * F + i] = sh[i];

    // --- deg: 64 n's per block, 4 threads per n split the m-range
    const int nl = threadIdx.x & 63;
    const int q  = threadIdx.x >> 6;                  // == wave id
    const int n  = nblk * 64 + nl;
    const float hv = sh[n];
    int cnt = 0;
    const int m0 = q * (F / 4);
    for (int m = 0; m < F / 4; m += 4) {
        float4 hm = *(const float4*)&sh[m0 + m];      // broadcast ds_read_b128
        cnt += (hv * hm.x > THRESH);
        cnt += (hv * hm.y > THRESH);
        cnt += (hv * hm.z > THRESH);
        cnt += (hv * hm.w > THRESH);
    }
    partial[q][nl] = cnt;
    __syncthreads();
    if (q == 0) {
        int deg = 1 + partial[0][nl] + partial[1][nl] + partial[2][nl] + partial[3][nl];
        dinv[b * F + n] = 1.0f / sqrtf((float)deg);
    }
}

// ---------------------------------------------------------------------------
// Kernel 3: out[b,n,m] = prelu2( dn * A[n,m] * dm ),  A = (sim>T) + I.
// One block per (b,n) row; float4 stores; hn/dinv (64 KB each) stay hot in
// L1/L2 — reads are cache hits, kernel is write-roofline-bound (~21 us for
// 128 MiB at 6.3 TB/s). This is the Round-0-measured-best structure.
// ---------------------------------------------------------------------------
__global__ __launch_bounds__(256) void out_kernel(const float* __restrict__ hn,
                                                  const float* __restrict__ dinv,
                                                  const float* __restrict__ p2,
                                                  float* __restrict__ out) {
    const int row = blockIdx.x;                       // b*F + n
    const int n   = row & (F - 1);
    const int bF  = row & ~(F - 1);                   // b*F
    const float hv = hn[row];
    const float dn = dinv[row];
    const float w2 = p2[0];
    const float4* hm4 = (const float4*)(hn + bF);
    const float4* dm4 = (const float4*)(dinv + bF);
    float4* o4 = (float4*)(out + (size_t)row * F);
    for (int t = threadIdx.x; t < F / 4; t += 256) {
        float4 hm = hm4[t];
        float4 dm = dm4[t];
        const int m = t * 4;
        float4 r;
        {
            float a = (hv * hm.x > THRESH) ? 1.f : 0.f; if (n == m + 0) a += 1.f;
            float v = (dn * a) * dm.x; r.x = (v >= 0.f) ? v : w2 * v;
        }
        {
            float a = (hv * hm.y > THRESH) ? 1.f : 0.f; if (n == m + 1) a += 1.f;
            float v = (dn * a) * dm.y; r.y = (v >= 0.f) ? v : w2 * v;
        }
        {
            float a = (hv * hm.z > THRESH) ? 1.f : 0.f; if (n == m + 2) a += 1.f;
            float v = (dn * a) * dm.z; r.z = (v >= 0.f) ? v : w2 * v;
        }
        {
            float a = (hv * hm.w > THRESH) ? 1.f : 0.f; if (n == m + 3) a += 1.f;
            float v = (dn * a) * dm.w; r.w = (v >= 0.f) ? v : w2 * v;
        }
        o4[t] = r;
    }
}

extern "C" void kernel_launch(void* const* d_in, const int* in_sizes, int n_in,
                              void* d_out, int out_size, void* d_ws, size_t ws_size,
                              hipStream_t stream) {
    const float* x   = (const float*)d_in[0];
    const float* p1  = (const float*)d_in[1];
    const float* p2  = (const float*)d_in[2];
    const float* bnw = (const float*)d_in[3];
    const float* bnb = (const float*)d_in[4];
    float* out = (float*)d_out;

    float* h    = (float*)d_ws;            // B*F floats (pooled, pre-BN)
    float* hn   = h + B * F;               // B*F floats (normalized)
    float* dinv = hn + B * F;              // B*F floats

    pool_kernel<<<(B * F) / 4, 256, 0, stream>>>(x, p1, h);
    bndeg_kernel<<<B * (F / 64), 256, 0, stream>>>(h, bnw, bnb, hn, dinv);
    out_kernel<<<B * F, 256, 0, stream>>>(hn, dinv, p2, out);
}